// Round 1
// baseline (546.093 us; speedup 1.0000x reference)
//
#include <hip/hip_runtime.h>
#include <math.h>

#define NN 50000
#define NE 800000
#define DF 128
#define NC 16

// ---------------- degree / normalization ----------------
__global__ void k_deg_init(float* deg) {
    int i = blockIdx.x * blockDim.x + threadIdx.x;
    if (i < NN) deg[i] = 1.0f;  // self-loop contributes 1
}

__global__ void k_deg_edges(const int* __restrict__ dst, float* deg) {
    int i = blockIdx.x * blockDim.x + threadIdx.x;
    if (i < NE) atomicAdd(&deg[dst[i]], 1.0f);
}

__global__ void k_dis(float* deg) {
    int i = blockIdx.x * blockDim.x + threadIdx.x;
    if (i < NN) deg[i] = rsqrtf(deg[i]);  // deg >= 1 always
}

// ---------------- GEMM1: H1 = X @ W1  (50000x128 @ 128x128) ----------------
__global__ __launch_bounds__(256) void k_gemm1(const float* __restrict__ X,
                                               const float* __restrict__ W,
                                               float* __restrict__ H) {
    __shared__ float ws[DF * DF];   // 64 KB: full W1
    __shared__ float xs[16][DF];    // 8 KB: 16 rows of X
    const int row0 = blockIdx.x * 16;

    for (int i = threadIdx.x; i < DF * DF; i += 256) ws[i] = W[i];
    for (int i = threadIdx.x; i < 16 * DF; i += 256) {
        int r = i >> 7, c = i & 127;
        int gr = row0 + r;
        xs[r][c] = (gr < NN) ? X[(long long)gr * DF + c] : 0.0f;
    }
    __syncthreads();

    const int col = threadIdx.x & 127;
    const int rbase = threadIdx.x >> 7;  // 0 or 1
    float acc[8];
#pragma unroll
    for (int i = 0; i < 8; ++i) acc[i] = 0.0f;

    for (int k = 0; k < DF; ++k) {
        float w = ws[k * DF + col];
#pragma unroll
        for (int i = 0; i < 8; ++i) acc[i] += xs[rbase + 2 * i][k] * w;
    }
#pragma unroll
    for (int i = 0; i < 8; ++i) {
        int gr = row0 + rbase + 2 * i;
        if (gr < NN) H[(long long)gr * DF + col] = acc[i];
    }
}

// ---------------- AGG1 init: bias + self-loop ----------------
__global__ void k_agg1_init(const float* __restrict__ H1,
                            const float* __restrict__ dis,
                            const float* __restrict__ b1,
                            float* __restrict__ AGG) {
    int i = blockIdx.x * blockDim.x + threadIdx.x;
    if (i < NN * DF) {
        int node = i >> 7, f = i & 127;
        float d = dis[node];
        AGG[i] = b1[f] + H1[i] * d * d;
    }
}

// ---------------- scatter layer 1: AGG[dst] += H1[src]*norm ----------------
__global__ void k_scatter1(const int* __restrict__ src,
                           const int* __restrict__ dst,
                           const float* __restrict__ dis,
                           const float* __restrict__ H1,
                           float* __restrict__ AGG) {
    long long i = (long long)blockIdx.x * blockDim.x + threadIdx.x;
    if (i < (long long)NE * DF) {
        int e = (int)(i >> 7), f = (int)(i & 127);
        int s = src[e], d = dst[e];
        float nrm = dis[s] * dis[d];
        atomicAdd(&AGG[(long long)d * DF + f], H1[(long long)s * DF + f] * nrm);
    }
}

// ---------------- GEMM2: H2 = relu(AGG1) @ W2  (50000x128 @ 128x16) --------
__global__ __launch_bounds__(256) void k_gemm2(const float* __restrict__ A,
                                               const float* __restrict__ W2,
                                               float* __restrict__ H2) {
    __shared__ float ws[DF * NC];       // 8 KB
    __shared__ float xs[16][DF + 1];    // padded: avoid 4-way bank conflict
    const int row0 = blockIdx.x * 16;

    for (int i = threadIdx.x; i < DF * NC; i += 256) ws[i] = W2[i];
    for (int i = threadIdx.x; i < 16 * DF; i += 256) {
        int r = i >> 7, c = i & 127;
        int gr = row0 + r;
        float v = (gr < NN) ? A[(long long)gr * DF + c] : 0.0f;
        xs[r][c] = fmaxf(v, 0.0f);  // fused ReLU
    }
    __syncthreads();

    const int col = threadIdx.x & 15;
    const int row = threadIdx.x >> 4;
    float acc = 0.0f;
    for (int k = 0; k < DF; ++k) acc += xs[row][k] * ws[k * NC + col];

    int gr = row0 + row;
    if (gr < NN) H2[(long long)gr * NC + col] = acc;
}

// ---------------- out init: bias + self-loop ----------------
__global__ void k_out_init(const float* __restrict__ H2,
                           const float* __restrict__ dis,
                           const float* __restrict__ b2,
                           float* __restrict__ OUT) {
    int i = blockIdx.x * blockDim.x + threadIdx.x;
    if (i < NN * NC) {
        int node = i >> 4, c = i & 15;
        float d = dis[node];
        OUT[i] = b2[c] + H2[i] * d * d;
    }
}

// ---------------- scatter layer 2 ----------------
__global__ void k_scatter2(const int* __restrict__ src,
                           const int* __restrict__ dst,
                           const float* __restrict__ dis,
                           const float* __restrict__ H2,
                           float* __restrict__ OUT) {
    long long i = (long long)blockIdx.x * blockDim.x + threadIdx.x;
    if (i < (long long)NE * NC) {
        int e = (int)(i >> 4), c = (int)(i & 15);
        int s = src[e], d = dst[e];
        float nrm = dis[s] * dis[d];
        atomicAdd(&OUT[(long long)d * NC + c], H2[(long long)s * NC + c] * nrm);
    }
}

// ---------------- sigmoid in place ----------------
__global__ void k_sigmoid(float* __restrict__ OUT) {
    int i = blockIdx.x * blockDim.x + threadIdx.x;
    if (i < NN * NC) {
        float v = OUT[i];
        OUT[i] = 1.0f / (1.0f + expf(-v));
    }
}

extern "C" void kernel_launch(void* const* d_in, const int* in_sizes, int n_in,
                              void* d_out, int out_size, void* d_ws, size_t ws_size,
                              hipStream_t stream) {
    const float* X  = (const float*)d_in[0];
    const int*   EI = (const int*)d_in[1];     // [2, NE] row-major
    const float* W1 = (const float*)d_in[2];
    const float* b1 = (const float*)d_in[3];
    const float* W2 = (const float*)d_in[4];
    const float* b2 = (const float*)d_in[5];
    float* OUT = (float*)d_out;

    const int* src = EI;
    const int* dst = EI + NE;

    // workspace layout (aligned to 512B)
    char* ws = (char*)d_ws;
    float* dis  = (float*)(ws);                       // NN floats (deg -> dis in place)
    float* H1   = (float*)(ws + 204800);              // NN*DF floats
    float* AGG1 = (float*)(ws + 204800 + 25600000);   // NN*DF floats
    float* H2   = H1;                                  // reuse: H1 dead after scatter1

    const int B = 256;

    k_deg_init<<<(NN + B - 1) / B, B, 0, stream>>>(dis);
    k_deg_edges<<<(NE + B - 1) / B, B, 0, stream>>>(dst, dis);
    k_dis<<<(NN + B - 1) / B, B, 0, stream>>>(dis);

    k_gemm1<<<(NN + 15) / 16, B, 0, stream>>>(X, W1, H1);

    k_agg1_init<<<(NN * DF + B - 1) / B, B, 0, stream>>>(H1, dis, b1, AGG1);
    k_scatter1<<<(int)(((long long)NE * DF + B - 1) / B), B, 0, stream>>>(src, dst, dis, H1, AGG1);

    k_gemm2<<<(NN + 15) / 16, B, 0, stream>>>(AGG1, W2, H2);

    k_out_init<<<(NN * NC + B - 1) / B, B, 0, stream>>>(H2, dis, b2, OUT);
    k_scatter2<<<(int)(((long long)NE * NC + B - 1) / B), B, 0, stream>>>(src, dst, dis, H2, OUT);
    k_sigmoid<<<(NN * NC + B - 1) / B, B, 0, stream>>>(OUT);
}

// Round 3
// 387.823 us; speedup vs baseline: 1.4081x; 1.4081x over previous
//
#include <hip/hip_runtime.h>
#include <math.h>

#define NN 50000
#define NE 800000
#define DF 128
#define NC 16

// ---------------- init: deg=1 (self loop), cnt=0 ----------------
__global__ void k_deg_init(float* deg, int* cnt) {
    int i = blockIdx.x * blockDim.x + threadIdx.x;
    if (i < NN) { deg[i] = 1.0f; cnt[i] = 0; }
}

__global__ void k_deg_edges(const int* __restrict__ dst, float* deg) {
    int i = blockIdx.x * blockDim.x + threadIdx.x;
    if (i < NE) atomicAdd(&deg[dst[i]], 1.0f);
}

__global__ void k_dis(float* deg) {
    int i = blockIdx.x * blockDim.x + threadIdx.x;
    if (i < NN) deg[i] = rsqrtf(deg[i]);
}

// ---------------- exclusive scan of (deg-1) -> CSR offsets ----------------
__global__ __launch_bounds__(1024) void k_scan(const float* __restrict__ deg,
                                               int* __restrict__ off) {
    __shared__ int part[1024];
    const int T = 1024, C = (NN + T - 1) / T;  // 49 elems/thread
    int t = threadIdx.x;
    int base = t * C;
    int s = 0;
    for (int i = 0; i < C; ++i) {
        int idx = base + i;
        if (idx < NN) s += (int)deg[idx] - 1;  // real in-edges only
    }
    part[t] = s;
    __syncthreads();
    for (int o = 1; o < T; o <<= 1) {
        int v = (t >= o) ? part[t - o] : 0;
        __syncthreads();
        part[t] += v;
        __syncthreads();
    }
    int run = (t > 0) ? part[t - 1] : 0;
    for (int i = 0; i < C; ++i) {
        int idx = base + i;
        if (idx < NN) { off[idx] = run; run += (int)deg[idx] - 1; }
    }
    if (t == T - 1) off[NN] = part[T - 1];
}

// ---------------- CSR fill: rec[pos] = (src, dis[src]*dis[dst]) ----------------
__global__ void k_csr_fill(const int* __restrict__ src, const int* __restrict__ dst,
                           const float* __restrict__ dis, const int* __restrict__ off,
                           int* __restrict__ cnt, int2* __restrict__ rec) {
    int e = blockIdx.x * blockDim.x + threadIdx.x;
    if (e < NE) {
        int s = src[e], d = dst[e];
        int pos = off[d] + atomicAdd(&cnt[d], 1);
        float w = dis[s] * dis[d];
        rec[pos] = make_int2(s, __float_as_int(w));
    }
}

// ---------------- GEMM1: H1 = X @ W1  (50000x128 @ 128x128) ----------------
__global__ __launch_bounds__(256) void k_gemm1(const float* __restrict__ X,
                                               const float* __restrict__ W,
                                               float* __restrict__ H) {
    __shared__ float ws[DF * DF];
    __shared__ float xs[16][DF];
    const int row0 = blockIdx.x * 16;

    for (int i = threadIdx.x; i < DF * DF; i += 256) ws[i] = W[i];
    for (int i = threadIdx.x; i < 16 * DF; i += 256) {
        int r = i >> 7, c = i & 127;
        int gr = row0 + r;
        xs[r][c] = (gr < NN) ? X[(long long)gr * DF + c] : 0.0f;
    }
    __syncthreads();

    const int col = threadIdx.x & 127;
    const int rbase = threadIdx.x >> 7;
    float acc[8];
#pragma unroll
    for (int i = 0; i < 8; ++i) acc[i] = 0.0f;

    for (int k = 0; k < DF; ++k) {
        float w = ws[k * DF + col];
#pragma unroll
        for (int i = 0; i < 8; ++i) acc[i] += xs[rbase + 2 * i][k] * w;
    }
#pragma unroll
    for (int i = 0; i < 8; ++i) {
        int gr = row0 + rbase + 2 * i;
        if (gr < NN) H[(long long)gr * DF + col] = acc[i];
    }
}

// ---------------- agg layer 1: one node per wave, fused bias+self+ReLU ------
__global__ __launch_bounds__(256) void k_agg1(const float* __restrict__ H1,
                                              const float* __restrict__ dis,
                                              const float* __restrict__ b1,
                                              const int* __restrict__ off,
                                              const int2* __restrict__ rec,
                                              float* __restrict__ AGG) {
    const int wid = threadIdx.x >> 6, lane = threadIdx.x & 63;
    const int n = blockIdx.x * 4 + wid;
    if (n >= NN) return;

    float2 bb = *(const float2*)&b1[2 * lane];
    float dn = dis[n];
    float2 hs = *(const float2*)&H1[(size_t)n * DF + 2 * lane];
    float accx = bb.x + hs.x * dn * dn;
    float accy = bb.y + hs.y * dn * dn;

    const int e0 = off[n], e1 = off[n + 1];
    for (int e = e0; e < e1; ++e) {
        int2 r = rec[e];                       // wave-uniform broadcast load
        float w = __int_as_float(r.y);
        float2 h = *(const float2*)&H1[(size_t)r.x * DF + 2 * lane];
        accx += h.x * w;
        accy += h.y * w;
    }
    float2 o = { fmaxf(accx, 0.0f), fmaxf(accy, 0.0f) };  // fused ReLU
    *(float2*)&AGG[(size_t)n * DF + 2 * lane] = o;
}

// ---------------- GEMM2: H2 = AGG1 @ W2  (50000x128 @ 128x16) ----------------
__global__ __launch_bounds__(256) void k_gemm2(const float* __restrict__ A,
                                               const float* __restrict__ W2,
                                               float* __restrict__ H2) {
    __shared__ float ws[DF * NC];
    __shared__ float xs[16][DF + 1];
    const int row0 = blockIdx.x * 16;

    for (int i = threadIdx.x; i < DF * NC; i += 256) ws[i] = W2[i];
    for (int i = threadIdx.x; i < 16 * DF; i += 256) {
        int r = i >> 7, c = i & 127;
        int gr = row0 + r;
        xs[r][c] = (gr < NN) ? A[(long long)gr * DF + c] : 0.0f;  // AGG already ReLU'd
    }
    __syncthreads();

    const int col = threadIdx.x & 15;
    const int row = threadIdx.x >> 4;
    float acc = 0.0f;
    for (int k = 0; k < DF; ++k) acc += xs[row][k] * ws[k * NC + col];

    int gr = row0 + row;
    if (gr < NN) H2[(long long)gr * NC + col] = acc;
}

// ---------------- agg layer 2: fused bias+self+sigmoid -> OUT ----------------
// one node per wave; 4 subgroups of 16 lanes process 4 edges in parallel
__global__ __launch_bounds__(256) void k_agg2(const float* __restrict__ H2,
                                              const float* __restrict__ dis,
                                              const float* __restrict__ b2,
                                              const int* __restrict__ off,
                                              const int2* __restrict__ rec,
                                              float* __restrict__ OUT) {
    const int wid = threadIdx.x >> 6, lane = threadIdx.x & 63;
    const int n = blockIdx.x * 4 + wid;
    if (n >= NN) return;

    const int f = lane & 15, g = lane >> 4;
    float acc = 0.0f;
    const int e0 = off[n], e1 = off[n + 1];
    for (int e = e0 + g; e < e1; e += 4) {
        int2 r = rec[e];
        float w = __int_as_float(r.y);
        acc += H2[(size_t)r.x * NC + f] * w;
    }
    acc += __shfl_down(acc, 32);
    acc += __shfl_down(acc, 16);
    if (g == 0) {
        float dn = dis[n];
        float v = b2[f] + H2[(size_t)n * NC + f] * dn * dn + acc;
        OUT[(size_t)n * NC + f] = 1.0f / (1.0f + expf(-v));
    }
}

extern "C" void kernel_launch(void* const* d_in, const int* in_sizes, int n_in,
                              void* d_out, int out_size, void* d_ws, size_t ws_size,
                              hipStream_t stream) {
    const float* X  = (const float*)d_in[0];
    const int*   EI = (const int*)d_in[1];
    const float* W1 = (const float*)d_in[2];
    const float* b1 = (const float*)d_in[3];
    const float* W2 = (const float*)d_in[4];
    const float* b2 = (const float*)d_in[5];
    float* OUT = (float*)d_out;

    const int* src = EI;
    const int* dst = EI + NE;

    // workspace layout (bytes)
    char* ws = (char*)d_ws;
    int*   off = (int*)(ws);                     // (NN+1) ints
    int*   cnt = (int*)(ws + 262144);            // NN ints
    float* dis = (float*)(ws + 524288);          // NN floats (deg -> dis in place)
    int2*  rec = (int2*)(ws + 786432);           // NE int2 = 6.4 MB
    float* H1  = (float*)(ws + 8388608);         // NN*DF floats = 25.6 MB
    float* AGG = (float*)(ws + 33988608);        // NN*DF floats = 25.6 MB
    float* H2  = H1;                             // H1 dead after k_agg1

    const int B = 256;

    k_deg_init<<<(NN + B - 1) / B, B, 0, stream>>>(dis, cnt);
    k_deg_edges<<<(NE + B - 1) / B, B, 0, stream>>>(dst, dis);
    k_scan<<<1, 1024, 0, stream>>>(dis, off);     // reads integer degrees
    k_dis<<<(NN + B - 1) / B, B, 0, stream>>>(dis);  // deg -> rsqrt(deg) in place
    k_csr_fill<<<(NE + B - 1) / B, B, 0, stream>>>(src, dst, dis, off, cnt, rec);

    k_gemm1<<<(NN + 15) / 16, B, 0, stream>>>(X, W1, H1);
    k_agg1<<<(NN + 3) / 4, B, 0, stream>>>(H1, dis, b1, off, rec, AGG);
    k_gemm2<<<(NN + 15) / 16, B, 0, stream>>>(AGG, W2, H2);
    k_agg2<<<(NN + 3) / 4, B, 0, stream>>>(H2, dis, b2, off, rec, OUT);
}

// Round 4
// 266.787 us; speedup vs baseline: 2.0469x; 1.4537x over previous
//
#include <hip/hip_runtime.h>
#include <math.h>

#define NN 50000
#define NE 800000
#define DF 128
#define NC 16
#define NBLK 200   // scan blocks
#define CHUNK 250  // elements per scan block (NBLK*CHUNK == NN)

// ---------------- init: degi=0, cnt=0 ----------------
__global__ void k_deg_init(int* degi, int* cnt) {
    int i = blockIdx.x * blockDim.x + threadIdx.x;
    if (i < NN) { degi[i] = 0; cnt[i] = 0; }
}

__global__ void k_deg_edges(const int* __restrict__ dst, int* degi) {
    int i = blockIdx.x * blockDim.x + threadIdx.x;
    if (i < NE) atomicAdd(&degi[dst[i]], 1);
}

// ---------------- phase 1: per-block partial sums of degi ----------------
__global__ __launch_bounds__(256) void k_part(const int* __restrict__ degi,
                                              int* __restrict__ part) {
    __shared__ int ws[4];
    const int b = blockIdx.x, t = threadIdx.x;
    int s = 0;
    if (t < CHUNK) s = degi[b * CHUNK + t];   // CHUNK <= 256
    // wave reduce
    for (int o = 32; o > 0; o >>= 1) s += __shfl_down(s, o);
    if ((t & 63) == 0) ws[t >> 6] = s;
    __syncthreads();
    if (t == 0) part[b] = ws[0] + ws[1] + ws[2] + ws[3];
}

// ---------------- phase 2: scan the NBLK partials (single tiny block) -------
__global__ __launch_bounds__(256) void k_scan_part(const int* __restrict__ part,
                                                   int* __restrict__ partoff,
                                                   int* __restrict__ off) {
    __shared__ int s[256];
    const int t = threadIdx.x;
    int v = (t < NBLK) ? part[t] : 0;
    s[t] = v;
    __syncthreads();
    for (int o = 1; o < 256; o <<= 1) {
        int x = (t >= o) ? s[t - o] : 0;
        __syncthreads();
        s[t] += x;
        __syncthreads();
    }
    if (t < NBLK) partoff[t] = s[t] - v;   // exclusive
    if (t == 255) off[NN] = s[255];        // total = NE
}

// ---------------- phase 3: block-local scan -> offsets; fused dis ----------
__global__ __launch_bounds__(256) void k_off(const int* __restrict__ degi,
                                             const int* __restrict__ partoff,
                                             int* __restrict__ off,
                                             float* __restrict__ dis) {
    __shared__ int s[256];
    const int b = blockIdx.x, t = threadIdx.x;
    const int idx = b * CHUNK + t;
    int v = (t < CHUNK) ? degi[idx] : 0;
    s[t] = v;
    __syncthreads();
    for (int o = 1; o < 256; o <<= 1) {
        int x = (t >= o) ? s[t - o] : 0;
        __syncthreads();
        s[t] += x;
        __syncthreads();
    }
    if (t < CHUNK) {
        off[idx] = partoff[b] + s[t] - v;                 // exclusive prefix
        dis[idx] = rsqrtf((float)(v + 1));                // +1 self-loop
    }
}

// ---------------- CSR fill: rec[pos] = (src, dis[src]*dis[dst]) ----------------
__global__ void k_csr_fill(const int* __restrict__ src, const int* __restrict__ dst,
                           const float* __restrict__ dis, const int* __restrict__ off,
                           int* __restrict__ cnt, int2* __restrict__ rec) {
    int e = blockIdx.x * blockDim.x + threadIdx.x;
    if (e < NE) {
        int s = src[e], d = dst[e];
        int pos = off[d] + atomicAdd(&cnt[d], 1);
        float w = dis[s] * dis[d];
        rec[pos] = make_int2(s, __float_as_int(w));
    }
}

// ---------------- GEMM1: H1 = X @ W1  (50000x128 @ 128x128) ----------------
__global__ __launch_bounds__(256) void k_gemm1(const float* __restrict__ X,
                                               const float* __restrict__ W,
                                               float* __restrict__ H) {
    __shared__ float ws[DF * DF];
    __shared__ float xs[16][DF];
    const int row0 = blockIdx.x * 16;

    for (int i = threadIdx.x; i < DF * DF; i += 256) ws[i] = W[i];
    for (int i = threadIdx.x; i < 16 * DF; i += 256) {
        int r = i >> 7, c = i & 127;
        int gr = row0 + r;
        xs[r][c] = (gr < NN) ? X[(long long)gr * DF + c] : 0.0f;
    }
    __syncthreads();

    const int col = threadIdx.x & 127;
    const int rbase = threadIdx.x >> 7;
    float acc[8];
#pragma unroll
    for (int i = 0; i < 8; ++i) acc[i] = 0.0f;

    for (int k = 0; k < DF; ++k) {
        float w = ws[k * DF + col];
#pragma unroll
        for (int i = 0; i < 8; ++i) acc[i] += xs[rbase + 2 * i][k] * w;
    }
#pragma unroll
    for (int i = 0; i < 8; ++i) {
        int gr = row0 + rbase + 2 * i;
        if (gr < NN) H[(long long)gr * DF + col] = acc[i];
    }
}

// ---------------- agg layer 1: one node per wave, 2 edges/iter --------------
// lanes: half = lane>>5 picks edge parity, l32 = lane&31 covers 4 feats each
__global__ __launch_bounds__(256) void k_agg1(const float* __restrict__ H1,
                                              const float* __restrict__ dis,
                                              const float* __restrict__ b1,
                                              const int* __restrict__ off,
                                              const int2* __restrict__ rec,
                                              float* __restrict__ AGG) {
    const int wid = threadIdx.x >> 6, lane = threadIdx.x & 63;
    const int n = blockIdx.x * 4 + wid;
    if (n >= NN) return;
    const int half = lane >> 5, l32 = lane & 31;

    const float4* H1v = (const float4*)H1;   // row stride DF/4 = 32
    float4 acc = make_float4(0.f, 0.f, 0.f, 0.f);
    if (half == 0) {
        float4 bb = ((const float4*)b1)[l32];
        float dn = dis[n];
        float4 hs = H1v[(size_t)n * 32 + l32];
        acc.x = bb.x + hs.x * dn * dn;
        acc.y = bb.y + hs.y * dn * dn;
        acc.z = bb.z + hs.z * dn * dn;
        acc.w = bb.w + hs.w * dn * dn;
    }

    const int e0 = off[n], e1 = off[n + 1];
    for (int e = e0 + half; e < e1; e += 2) {
        int2 r = rec[e];                       // uniform within each half-wave
        float w = __int_as_float(r.y);
        float4 h = H1v[(size_t)r.x * 32 + l32];
        acc.x += h.x * w;
        acc.y += h.y * w;
        acc.z += h.z * w;
        acc.w += h.w * w;
    }
    // butterfly-combine the two halves (both end with the full sum)
    acc.x += __shfl_xor(acc.x, 32);
    acc.y += __shfl_xor(acc.y, 32);
    acc.z += __shfl_xor(acc.z, 32);
    acc.w += __shfl_xor(acc.w, 32);
    if (half == 0) {
        float4 o = make_float4(fmaxf(acc.x, 0.f), fmaxf(acc.y, 0.f),
                               fmaxf(acc.z, 0.f), fmaxf(acc.w, 0.f));
        ((float4*)AGG)[(size_t)n * 32 + l32] = o;
    }
}

// ---------------- GEMM2: H2 = AGG1 @ W2  (50000x128 @ 128x16) ----------------
__global__ __launch_bounds__(256) void k_gemm2(const float* __restrict__ A,
                                               const float* __restrict__ W2,
                                               float* __restrict__ H2) {
    __shared__ float ws[DF * NC];
    __shared__ float xs[16][DF + 1];
    const int row0 = blockIdx.x * 16;

    for (int i = threadIdx.x; i < DF * NC; i += 256) ws[i] = W2[i];
    for (int i = threadIdx.x; i < 16 * DF; i += 256) {
        int r = i >> 7, c = i & 127;
        int gr = row0 + r;
        xs[r][c] = (gr < NN) ? A[(long long)gr * DF + c] : 0.0f;
    }
    __syncthreads();

    const int col = threadIdx.x & 15;
    const int row = threadIdx.x >> 4;
    float acc = 0.0f;
    for (int k = 0; k < DF; ++k) acc += xs[row][k] * ws[k * NC + col];

    int gr = row0 + row;
    if (gr < NN) H2[(long long)gr * NC + col] = acc;
}

// ---------------- agg layer 2: fused bias+self+sigmoid -> OUT ----------------
__global__ __launch_bounds__(256) void k_agg2(const float* __restrict__ H2,
                                              const float* __restrict__ dis,
                                              const float* __restrict__ b2,
                                              const int* __restrict__ off,
                                              const int2* __restrict__ rec,
                                              float* __restrict__ OUT) {
    const int wid = threadIdx.x >> 6, lane = threadIdx.x & 63;
    const int n = blockIdx.x * 4 + wid;
    if (n >= NN) return;

    const int f = lane & 15, g = lane >> 4;
    float acc = 0.0f;
    const int e0 = off[n], e1 = off[n + 1];
    for (int e = e0 + g; e < e1; e += 4) {
        int2 r = rec[e];
        float w = __int_as_float(r.y);
        acc += H2[(size_t)r.x * NC + f] * w;
    }
    acc += __shfl_down(acc, 32);
    acc += __shfl_down(acc, 16);
    if (g == 0) {
        float dn = dis[n];
        float v = b2[f] + H2[(size_t)n * NC + f] * dn * dn + acc;
        OUT[(size_t)n * NC + f] = 1.0f / (1.0f + expf(-v));
    }
}

extern "C" void kernel_launch(void* const* d_in, const int* in_sizes, int n_in,
                              void* d_out, int out_size, void* d_ws, size_t ws_size,
                              hipStream_t stream) {
    const float* X  = (const float*)d_in[0];
    const int*   EI = (const int*)d_in[1];
    const float* W1 = (const float*)d_in[2];
    const float* b1 = (const float*)d_in[3];
    const float* W2 = (const float*)d_in[4];
    const float* b2 = (const float*)d_in[5];
    float* OUT = (float*)d_out;

    const int* src = EI;
    const int* dst = EI + NE;

    // workspace layout (bytes)
    char* ws = (char*)d_ws;
    int*   degi    = (int*)(ws);                 // NN ints
    int*   cnt     = (int*)(ws + 262144);        // NN ints
    int*   off     = (int*)(ws + 524288);        // NN+1 ints
    int*   part    = (int*)(ws + 786432);        // NBLK ints
    int*   partoff = (int*)(ws + 790528);        // NBLK ints
    float* dis     = (float*)(ws + 794624);      // NN floats
    int2*  rec     = (int2*)(ws + 1048576);      // NE int2 = 6.4 MB
    float* H1      = (float*)(ws + 8388608);     // NN*DF floats = 25.6 MB
    float* AGG     = (float*)(ws + 33988608);    // NN*DF floats = 25.6 MB
    float* H2      = H1;                         // H1 dead after k_agg1

    const int B = 256;

    k_deg_init<<<(NN + B - 1) / B, B, 0, stream>>>(degi, cnt);
    k_deg_edges<<<(NE + B - 1) / B, B, 0, stream>>>(dst, degi);
    k_part<<<NBLK, B, 0, stream>>>(degi, part);
    k_scan_part<<<1, B, 0, stream>>>(part, partoff, off);
    k_off<<<NBLK, B, 0, stream>>>(degi, partoff, off, dis);
    k_csr_fill<<<(NE + B - 1) / B, B, 0, stream>>>(src, dst, dis, off, cnt, rec);

    k_gemm1<<<(NN + 15) / 16, B, 0, stream>>>(X, W1, H1);
    k_agg1<<<(NN + 3) / 4, B, 0, stream>>>(H1, dis, b1, off, rec, AGG);
    k_gemm2<<<(NN + 15) / 16, B, 0, stream>>>(AGG, W2, H2);
    k_agg2<<<(NN + 3) / 4, B, 0, stream>>>(H2, dis, b2, off, rec, OUT);
}

// Round 5
// 206.776 us; speedup vs baseline: 2.6410x; 1.2902x over previous
//
#include <hip/hip_runtime.h>
#include <math.h>

#define NN 50000
#define NE 800000
#define DF 128
#define NC 16
#define NBLK 200   // scan blocks
#define CHUNK 250  // elements per scan block (NBLK*CHUNK == NN)

typedef __bf16 bf16x8 __attribute__((ext_vector_type(8)));
typedef __bf16 bf16x4 __attribute__((ext_vector_type(4)));
typedef float  f32x4  __attribute__((ext_vector_type(4)));

// ---------------- init: degi=0, cnt=0 ----------------
__global__ void k_deg_init(int* degi, int* cnt) {
    int i = blockIdx.x * blockDim.x + threadIdx.x;
    if (i < NN) { degi[i] = 0; cnt[i] = 0; }
}

__global__ void k_deg_edges(const int* __restrict__ dst, int* degi) {
    int i = blockIdx.x * blockDim.x + threadIdx.x;
    if (i < NE) atomicAdd(&degi[dst[i]], 1);
}

// ---------------- phase 1: per-block partial sums of degi ----------------
__global__ __launch_bounds__(256) void k_part(const int* __restrict__ degi,
                                              int* __restrict__ part) {
    __shared__ int ws[4];
    const int b = blockIdx.x, t = threadIdx.x;
    int s = 0;
    if (t < CHUNK) s = degi[b * CHUNK + t];
    for (int o = 32; o > 0; o >>= 1) s += __shfl_down(s, o);
    if ((t & 63) == 0) ws[t >> 6] = s;
    __syncthreads();
    if (t == 0) part[b] = ws[0] + ws[1] + ws[2] + ws[3];
}

// ---------------- phase 2: scan the NBLK partials ----------------
__global__ __launch_bounds__(256) void k_scan_part(const int* __restrict__ part,
                                                   int* __restrict__ partoff,
                                                   int* __restrict__ off) {
    __shared__ int s[256];
    const int t = threadIdx.x;
    int v = (t < NBLK) ? part[t] : 0;
    s[t] = v;
    __syncthreads();
    for (int o = 1; o < 256; o <<= 1) {
        int x = (t >= o) ? s[t - o] : 0;
        __syncthreads();
        s[t] += x;
        __syncthreads();
    }
    if (t < NBLK) partoff[t] = s[t] - v;
    if (t == 255) off[NN] = s[255];
}

// ---------------- phase 3: block-local scan -> offsets; fused dis ----------
__global__ __launch_bounds__(256) void k_off(const int* __restrict__ degi,
                                             const int* __restrict__ partoff,
                                             int* __restrict__ off,
                                             float* __restrict__ dis) {
    __shared__ int s[256];
    const int b = blockIdx.x, t = threadIdx.x;
    const int idx = b * CHUNK + t;
    int v = (t < CHUNK) ? degi[idx] : 0;
    s[t] = v;
    __syncthreads();
    for (int o = 1; o < 256; o <<= 1) {
        int x = (t >= o) ? s[t - o] : 0;
        __syncthreads();
        s[t] += x;
        __syncthreads();
    }
    if (t < CHUNK) {
        off[idx] = partoff[b] + s[t] - v;
        dis[idx] = rsqrtf((float)(v + 1));   // +1 self-loop
    }
}

// ---------------- CSR fill ----------------
__global__ void k_csr_fill(const int* __restrict__ src, const int* __restrict__ dst,
                           const float* __restrict__ dis, const int* __restrict__ off,
                           int* __restrict__ cnt, int2* __restrict__ rec) {
    int e = blockIdx.x * blockDim.x + threadIdx.x;
    if (e < NE) {
        int s = src[e], d = dst[e];
        int pos = off[d] + atomicAdd(&cnt[d], 1);
        float w = dis[s] * dis[d];
        rec[pos] = make_int2(s, __float_as_int(w));
    }
}

// ---------------- convert X -> bf16 ----------------
__global__ void k_conv_x(const float4* __restrict__ X4, bf16x8* __restrict__ Xb) {
    int i = blockIdx.x * blockDim.x + threadIdx.x;
    if (i < NN * DF / 8) {
        float4 a = X4[2 * i], b = X4[2 * i + 1];
        bf16x8 o;
        o[0] = (__bf16)a.x; o[1] = (__bf16)a.y; o[2] = (__bf16)a.z; o[3] = (__bf16)a.w;
        o[4] = (__bf16)b.x; o[5] = (__bf16)b.y; o[6] = (__bf16)b.z; o[7] = (__bf16)b.w;
        Xb[i] = o;
    }
}

// ---------------- convert W1 -> W1T bf16 [128][128], W2 -> W2T bf16 [16][128]
__global__ void k_conv_w(const float* __restrict__ W1, const float* __restrict__ W2,
                         __bf16* __restrict__ W1T, __bf16* __restrict__ W2T) {
    int i = blockIdx.x * blockDim.x + threadIdx.x;
    if (i < DF * DF) {
        int n = i >> 7, k = i & 127;
        W1T[i] = (__bf16)W1[k * DF + n];
    }
    int j = i - DF * DF;
    if (j >= 0 && j < NC * DF) {
        int n = j >> 7, k = j & 127;
        W2T[j] = (__bf16)W2[k * NC + n];
    }
}

// ---------------- GEMM1 (MFMA): H1bf = bf16( Xbf @ W1 ) ----------------
// wave computes 16 rows x 128 cols via D' = mfma(W1T_frag, X_frag):
// lane l -> node m = m0+(l&15), feats n = nf*16 + (l>>4)*4 + i
__global__ __launch_bounds__(256) void k_gemm1(const __bf16* __restrict__ Xb,
                                               const __bf16* __restrict__ W1T,
                                               __bf16* __restrict__ H1) {
    const int wid = threadIdx.x >> 6, lane = threadIdx.x & 63;
    const int m0 = blockIdx.x * 64 + wid * 16;
    const int m = m0 + (lane & 15);
    const int mc = (m < NN) ? m : NN - 1;       // clamped load row
    const int kb = (lane >> 4) * 8;             // k-chunk within 32-slice

    f32x4 acc[8];
#pragma unroll
    for (int nf = 0; nf < 8; ++nf) acc[nf] = (f32x4){0.f, 0.f, 0.f, 0.f};

#pragma unroll
    for (int ks = 0; ks < 4; ++ks) {
        bf16x8 xa = *(const bf16x8*)&Xb[(size_t)mc * DF + ks * 32 + kb];
#pragma unroll
        for (int nf = 0; nf < 8; ++nf) {
            bf16x8 wa = *(const bf16x8*)&W1T[(size_t)(nf * 16 + (lane & 15)) * DF + ks * 32 + kb];
            acc[nf] = __builtin_amdgcn_mfma_f32_16x16x32_bf16(wa, xa, acc[nf], 0, 0, 0);
        }
    }
    if (m < NN) {
#pragma unroll
        for (int nf = 0; nf < 8; ++nf) {
            bf16x4 o;
            o[0] = (__bf16)acc[nf][0]; o[1] = (__bf16)acc[nf][1];
            o[2] = (__bf16)acc[nf][2]; o[3] = (__bf16)acc[nf][3];
            *(bf16x4*)&H1[(size_t)m * DF + nf * 16 + (lane >> 4) * 4] = o;
        }
    }
}

// ---------------- agg layer 1: one node per wave, 2 edges/iter, bf16 rows ---
__global__ __launch_bounds__(256) void k_agg1(const __bf16* __restrict__ H1,
                                              const float* __restrict__ dis,
                                              const float* __restrict__ b1,
                                              const int* __restrict__ off,
                                              const int2* __restrict__ rec,
                                              __bf16* __restrict__ AGG) {
    const int wid = threadIdx.x >> 6, lane = threadIdx.x & 63;
    const int n = blockIdx.x * 4 + wid;
    if (n >= NN) return;
    const int half = lane >> 5, l32 = lane & 31;
    const int fo = l32 * 4;

    float a0 = 0.f, a1 = 0.f, a2 = 0.f, a3 = 0.f;
    if (half == 0) {
        float4 bb = *(const float4*)&b1[fo];
        float dn = dis[n];
        bf16x4 hs = *(const bf16x4*)&H1[(size_t)n * DF + fo];
        a0 = bb.x + (float)hs[0] * dn * dn;
        a1 = bb.y + (float)hs[1] * dn * dn;
        a2 = bb.z + (float)hs[2] * dn * dn;
        a3 = bb.w + (float)hs[3] * dn * dn;
    }

    const int e0 = off[n], e1 = off[n + 1];
    for (int e = e0 + half; e < e1; e += 2) {
        int2 r = rec[e];
        float w = __int_as_float(r.y);
        bf16x4 h = *(const bf16x4*)&H1[(size_t)r.x * DF + fo];
        a0 += (float)h[0] * w;
        a1 += (float)h[1] * w;
        a2 += (float)h[2] * w;
        a3 += (float)h[3] * w;
    }
    a0 += __shfl_xor(a0, 32);
    a1 += __shfl_xor(a1, 32);
    a2 += __shfl_xor(a2, 32);
    a3 += __shfl_xor(a3, 32);
    if (half == 0) {
        bf16x4 o;
        o[0] = (__bf16)fmaxf(a0, 0.f);
        o[1] = (__bf16)fmaxf(a1, 0.f);
        o[2] = (__bf16)fmaxf(a2, 0.f);
        o[3] = (__bf16)fmaxf(a3, 0.f);
        *(bf16x4*)&AGG[(size_t)n * DF + fo] = o;
    }
}

// ---------------- GEMM2 (MFMA): H2 = AGG @ W2  (f32 out) ----------------
__global__ __launch_bounds__(256) void k_gemm2(const __bf16* __restrict__ A,
                                               const __bf16* __restrict__ W2T,
                                               float* __restrict__ H2) {
    const int wid = threadIdx.x >> 6, lane = threadIdx.x & 63;
    const int m0 = blockIdx.x * 64 + wid * 16;
    const int m = m0 + (lane & 15);
    const int mc = (m < NN) ? m : NN - 1;
    const int kb = (lane >> 4) * 8;

    f32x4 acc = (f32x4){0.f, 0.f, 0.f, 0.f};
#pragma unroll
    for (int ks = 0; ks < 4; ++ks) {
        bf16x8 xa = *(const bf16x8*)&A[(size_t)mc * DF + ks * 32 + kb];
        bf16x8 wa = *(const bf16x8*)&W2T[(size_t)(lane & 15) * DF + ks * 32 + kb];
        acc = __builtin_amdgcn_mfma_f32_16x16x32_bf16(wa, xa, acc, 0, 0, 0);
    }
    if (m < NN) *(f32x4*)&H2[(size_t)m * NC + (lane >> 4) * 4] = acc;
}

// ---------------- agg layer 2: fused bias+self+sigmoid -> OUT ----------------
__global__ __launch_bounds__(256) void k_agg2(const float* __restrict__ H2,
                                              const float* __restrict__ dis,
                                              const float* __restrict__ b2,
                                              const int* __restrict__ off,
                                              const int2* __restrict__ rec,
                                              float* __restrict__ OUT) {
    const int wid = threadIdx.x >> 6, lane = threadIdx.x & 63;
    const int n = blockIdx.x * 4 + wid;
    if (n >= NN) return;

    const int f = lane & 15, g = lane >> 4;
    float acc = 0.0f;
    const int e0 = off[n], e1 = off[n + 1];
    for (int e = e0 + g; e < e1; e += 4) {
        int2 r = rec[e];
        float w = __int_as_float(r.y);
        acc += H2[(size_t)r.x * NC + f] * w;
    }
    acc += __shfl_down(acc, 32);
    acc += __shfl_down(acc, 16);
    if (g == 0) {
        float dn = dis[n];
        float v = b2[f] + H2[(size_t)n * NC + f] * dn * dn + acc;
        OUT[(size_t)n * NC + f] = 1.0f / (1.0f + expf(-v));
    }
}

extern "C" void kernel_launch(void* const* d_in, const int* in_sizes, int n_in,
                              void* d_out, int out_size, void* d_ws, size_t ws_size,
                              hipStream_t stream) {
    const float* X  = (const float*)d_in[0];
    const int*   EI = (const int*)d_in[1];
    const float* W1 = (const float*)d_in[2];
    const float* b1 = (const float*)d_in[3];
    const float* W2 = (const float*)d_in[4];
    const float* b2 = (const float*)d_in[5];
    float* OUT = (float*)d_out;

    const int* src = EI;
    const int* dst = EI + NE;

    // workspace layout (bytes)
    char* ws = (char*)d_ws;
    int*    degi    = (int*)(ws);                   // NN
    int*    cnt     = (int*)(ws + 262144);          // NN
    int*    off     = (int*)(ws + 524288);          // NN+1
    int*    part    = (int*)(ws + 786432);          // NBLK
    int*    partoff = (int*)(ws + 790528);          // NBLK
    float*  dis     = (float*)(ws + 794624);        // NN
    int2*   rec     = (int2*)(ws + 1048576);        // NE int2 = 6.4 MB
    __bf16* Xbf     = (__bf16*)(ws + 8388608);      // NN*DF bf16 = 12.8 MB
    __bf16* W1T     = (__bf16*)(ws + 21188608);     // 128*128 bf16 = 32 KB
    __bf16* W2T     = (__bf16*)(ws + 21221376);     // 16*128 bf16 = 4 KB
    __bf16* H1      = (__bf16*)(ws + 21225472);     // NN*DF bf16 = 12.8 MB
    __bf16* AGG     = (__bf16*)(ws + 34025472);     // NN*DF bf16 = 12.8 MB
    float*  H2      = (float*)(ws + 46825472);      // NN*NC f32 = 3.2 MB

    const int B = 256;

    k_deg_init<<<(NN + B - 1) / B, B, 0, stream>>>(degi, cnt);
    k_deg_edges<<<(NE + B - 1) / B, B, 0, stream>>>(dst, degi);
    k_part<<<NBLK, B, 0, stream>>>(degi, part);
    k_scan_part<<<1, B, 0, stream>>>(part, partoff, off);
    k_off<<<NBLK, B, 0, stream>>>(degi, partoff, off, dis);
    k_csr_fill<<<(NE + B - 1) / B, B, 0, stream>>>(src, dst, dis, off, cnt, rec);

    k_conv_x<<<(NN * DF / 8 + B - 1) / B, B, 0, stream>>>((const float4*)X, (bf16x8*)Xbf);
    k_conv_w<<<(DF * DF + NC * DF + B - 1) / B, B, 0, stream>>>(W1, W2, W1T, W2T);

    k_gemm1<<<(NN + 63) / 64, B, 0, stream>>>(Xbf, W1T, H1);
    k_agg1<<<(NN + 3) / 4, B, 0, stream>>>(H1, dis, b1, off, rec, AGG);
    k_gemm2<<<(NN + 63) / 64, B, 0, stream>>>(AGG, W2T, H2);
    k_agg2<<<(NN + 3) / 4, B, 0, stream>>>(H2, dis, b2, off, rec, OUT);
}

// Round 6
// 182.054 us; speedup vs baseline: 2.9996x; 1.1358x over previous
//
#include <hip/hip_runtime.h>
#include <math.h>

#define NN 50000
#define NE 800000
#define DF 128
#define NC 16
#define NBLK 200   // scan blocks
#define CHUNK 250  // elements per scan block (NBLK*CHUNK == NN)

typedef __bf16 bf16x8 __attribute__((ext_vector_type(8)));
typedef __bf16 bf16x4 __attribute__((ext_vector_type(4)));
typedef float  f32x4  __attribute__((ext_vector_type(4)));

// ---------------- init: degi=0, cnt=0 ----------------
__global__ void k_deg_init(int* degi, int* cnt) {
    int i = blockIdx.x * blockDim.x + threadIdx.x;
    if (i < NN) { degi[i] = 0; cnt[i] = 0; }
}

__global__ void k_deg_edges(const int* __restrict__ dst, int* degi) {
    int i = blockIdx.x * blockDim.x + threadIdx.x;
    if (i < NE) atomicAdd(&degi[dst[i]], 1);
}

// ---------------- phase 1: per-block partial sums of degi ----------------
__global__ __launch_bounds__(256) void k_part(const int* __restrict__ degi,
                                              int* __restrict__ part) {
    __shared__ int ws[4];
    const int b = blockIdx.x, t = threadIdx.x;
    int s = 0;
    if (t < CHUNK) s = degi[b * CHUNK + t];
    for (int o = 32; o > 0; o >>= 1) s += __shfl_down(s, o);
    if ((t & 63) == 0) ws[t >> 6] = s;
    __syncthreads();
    if (t == 0) part[b] = ws[0] + ws[1] + ws[2] + ws[3];
}

// ---------------- phase 2: scan the NBLK partials ----------------
__global__ __launch_bounds__(256) void k_scan_part(const int* __restrict__ part,
                                                   int* __restrict__ partoff,
                                                   int* __restrict__ off) {
    __shared__ int s[256];
    const int t = threadIdx.x;
    int v = (t < NBLK) ? part[t] : 0;
    s[t] = v;
    __syncthreads();
    for (int o = 1; o < 256; o <<= 1) {
        int x = (t >= o) ? s[t - o] : 0;
        __syncthreads();
        s[t] += x;
        __syncthreads();
    }
    if (t < NBLK) partoff[t] = s[t] - v;
    if (t == 255) off[NN] = s[255];
}

// ---------------- phase 3: block-local scan -> offsets; fused dis ----------
__global__ __launch_bounds__(256) void k_off(const int* __restrict__ degi,
                                             const int* __restrict__ partoff,
                                             int* __restrict__ off,
                                             float* __restrict__ dis) {
    __shared__ int s[256];
    const int b = blockIdx.x, t = threadIdx.x;
    const int idx = b * CHUNK + t;
    int v = (t < CHUNK) ? degi[idx] : 0;
    s[t] = v;
    __syncthreads();
    for (int o = 1; o < 256; o <<= 1) {
        int x = (t >= o) ? s[t - o] : 0;
        __syncthreads();
        s[t] += x;
        __syncthreads();
    }
    if (t < CHUNK) {
        off[idx] = partoff[b] + s[t] - v;
        dis[idx] = rsqrtf((float)(v + 1));   // +1 self-loop
    }
}

// ---------------- CSR fill ----------------
__global__ void k_csr_fill(const int* __restrict__ src, const int* __restrict__ dst,
                           const float* __restrict__ dis, const int* __restrict__ off,
                           int* __restrict__ cnt, int2* __restrict__ rec) {
    int e = blockIdx.x * blockDim.x + threadIdx.x;
    if (e < NE) {
        int s = src[e], d = dst[e];
        int pos = off[d] + atomicAdd(&cnt[d], 1);
        float w = dis[s] * dis[d];
        rec[pos] = make_int2(s, __float_as_int(w));
    }
}

// ---------------- convert W1 -> W1T bf16 [128][128], W2 -> W2T bf16 [16][128]
__global__ void k_conv_w(const float* __restrict__ W1, const float* __restrict__ W2,
                         __bf16* __restrict__ W1T, __bf16* __restrict__ W2T) {
    int i = blockIdx.x * blockDim.x + threadIdx.x;
    if (i < DF * DF) {
        int n = i >> 7, k = i & 127;
        W1T[i] = (__bf16)W1[k * DF + n];
    }
    int j = i - DF * DF;
    if (j >= 0 && j < NC * DF) {
        int n = j >> 7, k = j & 127;
        W2T[j] = (__bf16)W2[k * NC + n];
    }
}

// ---------------- GEMM1 (MFMA): H1bf = bf16( X @ W1 ), f32->bf16 inline ----
// wave computes 16 rows x 128 cols via D' = mfma(W1T_frag, X_frag):
// lane l -> node m = m0+(l&15), feats n = nf*16 + (l>>4)*4 + i
__global__ __launch_bounds__(256) void k_gemm1(const float* __restrict__ X,
                                               const __bf16* __restrict__ W1T,
                                               __bf16* __restrict__ H1) {
    const int wid = threadIdx.x >> 6, lane = threadIdx.x & 63;
    const int m0 = blockIdx.x * 64 + wid * 16;
    const int m = m0 + (lane & 15);
    const int mc = (m < NN) ? m : NN - 1;       // clamped load row
    const int kb = (lane >> 4) * 8;             // k-chunk within 32-slice

    f32x4 acc[8];
#pragma unroll
    for (int nf = 0; nf < 8; ++nf) acc[nf] = (f32x4){0.f, 0.f, 0.f, 0.f};

#pragma unroll
    for (int ks = 0; ks < 4; ++ks) {
        float4 x0 = *(const float4*)&X[(size_t)mc * DF + ks * 32 + kb];
        float4 x1 = *(const float4*)&X[(size_t)mc * DF + ks * 32 + kb + 4];
        bf16x8 xa;
        xa[0] = (__bf16)x0.x; xa[1] = (__bf16)x0.y; xa[2] = (__bf16)x0.z; xa[3] = (__bf16)x0.w;
        xa[4] = (__bf16)x1.x; xa[5] = (__bf16)x1.y; xa[6] = (__bf16)x1.z; xa[7] = (__bf16)x1.w;
#pragma unroll
        for (int nf = 0; nf < 8; ++nf) {
            bf16x8 wa = *(const bf16x8*)&W1T[(size_t)(nf * 16 + (lane & 15)) * DF + ks * 32 + kb];
            acc[nf] = __builtin_amdgcn_mfma_f32_16x16x32_bf16(wa, xa, acc[nf], 0, 0, 0);
        }
    }
    if (m < NN) {
#pragma unroll
        for (int nf = 0; nf < 8; ++nf) {
            bf16x4 o;
            o[0] = (__bf16)acc[nf][0]; o[1] = (__bf16)acc[nf][1];
            o[2] = (__bf16)acc[nf][2]; o[3] = (__bf16)acc[nf][3];
            *(bf16x4*)&H1[(size_t)m * DF + nf * 16 + (lane >> 4) * 4] = o;
        }
    }
}

// ---------------- agg layer 1: one node per wave, 4 edges in flight ---------
// 4 groups of 16 lanes; each group owns one edge/iter; lane covers 8 feats
__global__ __launch_bounds__(256) void k_agg1(const __bf16* __restrict__ H1,
                                              const float* __restrict__ dis,
                                              const float* __restrict__ b1,
                                              const int* __restrict__ off,
                                              const int2* __restrict__ rec,
                                              __bf16* __restrict__ AGG) {
    const int wid = threadIdx.x >> 6, lane = threadIdx.x & 63;
    const int n = blockIdx.x * 4 + wid;
    if (n >= NN) return;
    const int g = lane >> 4, l16 = lane & 15;
    const int fo = l16 * 8;

    float a[8];
    if (g == 0) {
        float dn = dis[n], d2 = dn * dn;
        float4 b0 = *(const float4*)&b1[fo];
        float4 b4 = *(const float4*)&b1[fo + 4];
        bf16x8 hs = *(const bf16x8*)&H1[(size_t)n * DF + fo];
        a[0] = b0.x + (float)hs[0] * d2;
        a[1] = b0.y + (float)hs[1] * d2;
        a[2] = b0.z + (float)hs[2] * d2;
        a[3] = b0.w + (float)hs[3] * d2;
        a[4] = b4.x + (float)hs[4] * d2;
        a[5] = b4.y + (float)hs[5] * d2;
        a[6] = b4.z + (float)hs[6] * d2;
        a[7] = b4.w + (float)hs[7] * d2;
    } else {
#pragma unroll
        for (int i = 0; i < 8; ++i) a[i] = 0.f;
    }

    const int e0 = off[n], e1 = off[n + 1];
    for (int e = e0 + g; e < e1; e += 4) {
        int2 r = rec[e];                       // broadcast within 16-lane group
        float w = __int_as_float(r.y);
        bf16x8 h = *(const bf16x8*)&H1[(size_t)r.x * DF + fo];
#pragma unroll
        for (int i = 0; i < 8; ++i) a[i] += (float)h[i] * w;
    }
#pragma unroll
    for (int i = 0; i < 8; ++i) {
        a[i] += __shfl_xor(a[i], 16);
        a[i] += __shfl_xor(a[i], 32);
    }
    if (g == 0) {
        bf16x8 o;
#pragma unroll
        for (int i = 0; i < 8; ++i) o[i] = (__bf16)fmaxf(a[i], 0.f);
        *(bf16x8*)&AGG[(size_t)n * DF + fo] = o;
    }
}

// ---------------- GEMM2 (MFMA): H2 = AGG @ W2  (f32 out) ----------------
__global__ __launch_bounds__(256) void k_gemm2(const __bf16* __restrict__ A,
                                               const __bf16* __restrict__ W2T,
                                               float* __restrict__ H2) {
    const int wid = threadIdx.x >> 6, lane = threadIdx.x & 63;
    const int m0 = blockIdx.x * 64 + wid * 16;
    const int m = m0 + (lane & 15);
    const int mc = (m < NN) ? m : NN - 1;
    const int kb = (lane >> 4) * 8;

    f32x4 acc = (f32x4){0.f, 0.f, 0.f, 0.f};
#pragma unroll
    for (int ks = 0; ks < 4; ++ks) {
        bf16x8 xa = *(const bf16x8*)&A[(size_t)mc * DF + ks * 32 + kb];
        bf16x8 wa = *(const bf16x8*)&W2T[(size_t)(lane & 15) * DF + ks * 32 + kb];
        acc = __builtin_amdgcn_mfma_f32_16x16x32_bf16(wa, xa, acc, 0, 0, 0);
    }
    if (m < NN) *(f32x4*)&H2[(size_t)m * NC + (lane >> 4) * 4] = acc;
}

// ---------------- agg layer 2: 8 edges in flight, fused sigmoid -> OUT ------
// 8 groups of 8 lanes; each lane covers 2 classes as float2
__global__ __launch_bounds__(256) void k_agg2(const float* __restrict__ H2,
                                              const float* __restrict__ dis,
                                              const float* __restrict__ b2,
                                              const int* __restrict__ off,
                                              const int2* __restrict__ rec,
                                              float* __restrict__ OUT) {
    const int wid = threadIdx.x >> 6, lane = threadIdx.x & 63;
    const int n = blockIdx.x * 4 + wid;
    if (n >= NN) return;

    const int g = lane >> 3, l8 = lane & 7;
    float ax = 0.f, ay = 0.f;
    const int e0 = off[n], e1 = off[n + 1];
    for (int e = e0 + g; e < e1; e += 8) {
        int2 r = rec[e];
        float w = __int_as_float(r.y);
        float2 h = *(const float2*)&H2[(size_t)r.x * NC + l8 * 2];
        ax += h.x * w;
        ay += h.y * w;
    }
    ax += __shfl_xor(ax, 8);  ay += __shfl_xor(ay, 8);
    ax += __shfl_xor(ax, 16); ay += __shfl_xor(ay, 16);
    ax += __shfl_xor(ax, 32); ay += __shfl_xor(ay, 32);
    if (g == 0) {
        float dn = dis[n], d2 = dn * dn;
        float2 hs = *(const float2*)&H2[(size_t)n * NC + l8 * 2];
        float2 bb = *(const float2*)&b2[l8 * 2];
        float vx = bb.x + hs.x * d2 + ax;
        float vy = bb.y + hs.y * d2 + ay;
        float2 o = { 1.0f / (1.0f + expf(-vx)), 1.0f / (1.0f + expf(-vy)) };
        *(float2*)&OUT[(size_t)n * NC + l8 * 2] = o;
    }
}

extern "C" void kernel_launch(void* const* d_in, const int* in_sizes, int n_in,
                              void* d_out, int out_size, void* d_ws, size_t ws_size,
                              hipStream_t stream) {
    const float* X  = (const float*)d_in[0];
    const int*   EI = (const int*)d_in[1];
    const float* W1 = (const float*)d_in[2];
    const float* b1 = (const float*)d_in[3];
    const float* W2 = (const float*)d_in[4];
    const float* b2 = (const float*)d_in[5];
    float* OUT = (float*)d_out;

    const int* src = EI;
    const int* dst = EI + NE;

    // workspace layout (bytes)
    char* ws = (char*)d_ws;
    int*    degi    = (int*)(ws);                   // NN
    int*    cnt     = (int*)(ws + 262144);          // NN
    int*    off     = (int*)(ws + 524288);          // NN+1
    int*    part    = (int*)(ws + 786432);          // NBLK
    int*    partoff = (int*)(ws + 790528);          // NBLK
    float*  dis     = (float*)(ws + 794624);        // NN
    int2*   rec     = (int2*)(ws + 1048576);        // NE int2 = 6.4 MB
    __bf16* W1T     = (__bf16*)(ws + 8388608);      // 128*128 bf16 = 32 KB
    __bf16* W2T     = (__bf16*)(ws + 8421376);      // 16*128 bf16 = 4 KB
    __bf16* H1      = (__bf16*)(ws + 8425472);      // NN*DF bf16 = 12.8 MB
    __bf16* AGG     = (__bf16*)(ws + 21225472);     // NN*DF bf16 = 12.8 MB
    float*  H2      = (float*)(ws + 34025472);      // NN*NC f32 = 3.2 MB

    const int B = 256;

    k_deg_init<<<(NN + B - 1) / B, B, 0, stream>>>(degi, cnt);
    k_deg_edges<<<(NE + B - 1) / B, B, 0, stream>>>(dst, degi);
    k_part<<<NBLK, B, 0, stream>>>(degi, part);
    k_scan_part<<<1, B, 0, stream>>>(part, partoff, off);
    k_off<<<NBLK, B, 0, stream>>>(degi, partoff, off, dis);
    k_csr_fill<<<(NE + B - 1) / B, B, 0, stream>>>(src, dst, dis, off, cnt, rec);

    k_conv_w<<<(DF * DF + NC * DF + B - 1) / B, B, 0, stream>>>(W1, W2, W1T, W2T);

    k_gemm1<<<(NN + 63) / 64, B, 0, stream>>>(X, W1T, H1);
    k_agg1<<<(NN + 3) / 4, B, 0, stream>>>(H1, dis, b1, off, rec, AGG);
    k_gemm2<<<(NN + 63) / 64, B, 0, stream>>>(AGG, W2T, H2);
    k_agg2<<<(NN + 3) / 4, B, 0, stream>>>(H2, dis, b2, off, rec, OUT);
}

// Round 7
// 141.807 us; speedup vs baseline: 3.8509x; 1.2838x over previous
//
#include <hip/hip_runtime.h>
#include <math.h>

#define NN 50000
#define NE 800000
#define DF 128
#define NC 16
#define NBLK 200   // scan blocks
#define CHUNK 250  // elements per scan block (NBLK*CHUNK == NN)

typedef __bf16 bf16x8 __attribute__((ext_vector_type(8)));
typedef __bf16 bf16x4 __attribute__((ext_vector_type(4)));
typedef float  f32x4  __attribute__((ext_vector_type(4)));

#define GB ((NN + 63) / 64)    // gemm1 blocks in fused kernel (782)
#define DB ((NE + 255) / 256)  // deg/slot blocks in fused kernel (3125)

// ---------------- prep: degi=0  +  W1->W1T bf16, W2->W2T bf16 ----------------
__global__ void k_prep(int* __restrict__ degi,
                       const float* __restrict__ W1, const float* __restrict__ W2,
                       __bf16* __restrict__ W1T, __bf16* __restrict__ W2T) {
    int i = blockIdx.x * blockDim.x + threadIdx.x;
    if (i < NN) degi[i] = 0;
    int j = i - NN;
    if (j >= 0 && j < DF * DF) {
        int n = j >> 7, k = j & 127;
        W1T[j] = (__bf16)W1[k * DF + n];
    }
    int jj = j - DF * DF;
    if (jj >= 0 && jj < NC * DF) {
        int n = jj >> 7, k = jj & 127;
        W2T[jj] = (__bf16)W2[k * NC + n];
    }
}

// ---------------- fused: [0,GB) gemm1 (MFMA)  |  [GB,GB+DB) deg+slot ---------
// gemm1: H1bf = bf16( X @ W1 ); lane l -> node m0+(l&15), feats nf*16+(l>>4)*4+i
// deg:   slot[e] = atomicAdd(&degi[dst[e]], 1)   (coalesced slot store)
__global__ __launch_bounds__(256) void k_gemm1_deg(const float* __restrict__ X,
                                                   const __bf16* __restrict__ W1T,
                                                   __bf16* __restrict__ H1,
                                                   const int* __restrict__ dst,
                                                   int* __restrict__ degi,
                                                   int* __restrict__ slot) {
    if (blockIdx.x >= GB) {
        int e = (blockIdx.x - GB) * 256 + threadIdx.x;
        if (e < NE) slot[e] = atomicAdd(&degi[dst[e]], 1);
        return;
    }
    const int wid = threadIdx.x >> 6, lane = threadIdx.x & 63;
    const int m0 = blockIdx.x * 64 + wid * 16;
    const int m = m0 + (lane & 15);
    const int mc = (m < NN) ? m : NN - 1;       // clamped load row
    const int kb = (lane >> 4) * 8;             // k-chunk within 32-slice

    f32x4 acc[8];
#pragma unroll
    for (int nf = 0; nf < 8; ++nf) acc[nf] = (f32x4){0.f, 0.f, 0.f, 0.f};

#pragma unroll
    for (int ks = 0; ks < 4; ++ks) {
        float4 x0 = *(const float4*)&X[(size_t)mc * DF + ks * 32 + kb];
        float4 x1 = *(const float4*)&X[(size_t)mc * DF + ks * 32 + kb + 4];
        bf16x8 xa;
        xa[0] = (__bf16)x0.x; xa[1] = (__bf16)x0.y; xa[2] = (__bf16)x0.z; xa[3] = (__bf16)x0.w;
        xa[4] = (__bf16)x1.x; xa[5] = (__bf16)x1.y; xa[6] = (__bf16)x1.z; xa[7] = (__bf16)x1.w;
#pragma unroll
        for (int nf = 0; nf < 8; ++nf) {
            bf16x8 wa = *(const bf16x8*)&W1T[(size_t)(nf * 16 + (lane & 15)) * DF + ks * 32 + kb];
            acc[nf] = __builtin_amdgcn_mfma_f32_16x16x32_bf16(wa, xa, acc[nf], 0, 0, 0);
        }
    }
    if (m < NN) {
#pragma unroll
        for (int nf = 0; nf < 8; ++nf) {
            bf16x4 o;
            o[0] = (__bf16)acc[nf][0]; o[1] = (__bf16)acc[nf][1];
            o[2] = (__bf16)acc[nf][2]; o[3] = (__bf16)acc[nf][3];
            *(bf16x4*)&H1[(size_t)m * DF + nf * 16 + (lane >> 4) * 4] = o;
        }
    }
}

// ---------------- phase 1: per-block partial sums of degi ----------------
__global__ __launch_bounds__(256) void k_part(const int* __restrict__ degi,
                                              int* __restrict__ part) {
    __shared__ int ws[4];
    const int b = blockIdx.x, t = threadIdx.x;
    int s = 0;
    if (t < CHUNK) s = degi[b * CHUNK + t];
    for (int o = 32; o > 0; o >>= 1) s += __shfl_down(s, o);
    if ((t & 63) == 0) ws[t >> 6] = s;
    __syncthreads();
    if (t == 0) part[b] = ws[0] + ws[1] + ws[2] + ws[3];
}

// ---------------- phase 2: scan the NBLK partials ----------------
__global__ __launch_bounds__(256) void k_scan_part(const int* __restrict__ part,
                                                   int* __restrict__ partoff,
                                                   int* __restrict__ off) {
    __shared__ int s[256];
    const int t = threadIdx.x;
    int v = (t < NBLK) ? part[t] : 0;
    s[t] = v;
    __syncthreads();
    for (int o = 1; o < 256; o <<= 1) {
        int x = (t >= o) ? s[t - o] : 0;
        __syncthreads();
        s[t] += x;
        __syncthreads();
    }
    if (t < NBLK) partoff[t] = s[t] - v;
    if (t == 255) off[NN] = s[255];
}

// ---------------- phase 3: block-local scan -> offsets; fused dis ----------
__global__ __launch_bounds__(256) void k_off(const int* __restrict__ degi,
                                             const int* __restrict__ partoff,
                                             int* __restrict__ off,
                                             float* __restrict__ dis) {
    __shared__ int s[256];
    const int b = blockIdx.x, t = threadIdx.x;
    const int idx = b * CHUNK + t;
    int v = (t < CHUNK) ? degi[idx] : 0;
    s[t] = v;
    __syncthreads();
    for (int o = 1; o < 256; o <<= 1) {
        int x = (t >= o) ? s[t - o] : 0;
        __syncthreads();
        s[t] += x;
        __syncthreads();
    }
    if (t < CHUNK) {
        off[idx] = partoff[b] + s[t] - v;
        dis[idx] = rsqrtf((float)(v + 1));   // +1 self-loop
    }
}

// ---------------- CSR fill (atomic-free): rec[off[d]+slot[e]] = (s, w) ------
__global__ void k_csr_fill(const int* __restrict__ src, const int* __restrict__ dst,
                           const int* __restrict__ slot,
                           const float* __restrict__ dis, const int* __restrict__ off,
                           int2* __restrict__ rec) {
    int e = (blockIdx.x * blockDim.x + threadIdx.x) * 2;
#pragma unroll
    for (int u = 0; u < 2; ++u, ++e) {
        if (e < NE) {
            int s = src[e], d = dst[e];
            float w = dis[s] * dis[d];
            rec[off[d] + slot[e]] = make_int2(s, __float_as_int(w));
        }
    }
}

// ---------------- agg1 + gemm2 fused: one node per wave ---------------------
// gather/reduce 128-feat row in registers, ReLU, in-register 128x16 mini-GEMM,
// write H2[n][0:16] (f32). 4 groups of 16 lanes; lane covers 8 feats.
__global__ __launch_bounds__(256) void k_agg1g2(const __bf16* __restrict__ H1,
                                                const float* __restrict__ dis,
                                                const float* __restrict__ b1,
                                                const __bf16* __restrict__ W2T,
                                                const int* __restrict__ off,
                                                const int2* __restrict__ rec,
                                                float* __restrict__ H2) {
    const int wid = threadIdx.x >> 6, lane = threadIdx.x & 63;
    const int n = blockIdx.x * 4 + wid;
    if (n >= NN) return;
    const int g = lane >> 4, l16 = lane & 15;
    const int fo = l16 * 8;

    float a[8];
    if (g == 0) {
        float dn = dis[n], d2 = dn * dn;
        float4 b0 = *(const float4*)&b1[fo];
        float4 b4 = *(const float4*)&b1[fo + 4];
        bf16x8 hs = *(const bf16x8*)&H1[(size_t)n * DF + fo];
        a[0] = b0.x + (float)hs[0] * d2;
        a[1] = b0.y + (float)hs[1] * d2;
        a[2] = b0.z + (float)hs[2] * d2;
        a[3] = b0.w + (float)hs[3] * d2;
        a[4] = b4.x + (float)hs[4] * d2;
        a[5] = b4.y + (float)hs[5] * d2;
        a[6] = b4.z + (float)hs[6] * d2;
        a[7] = b4.w + (float)hs[7] * d2;
    } else {
#pragma unroll
        for (int i = 0; i < 8; ++i) a[i] = 0.f;
    }

    const int e0 = off[n], e1 = off[n + 1];
    int e = e0 + g;
    // 2 edges in flight per group (8 rows in flight per wave)
    for (; e + 4 < e1; e += 8) {
        int2 r0 = rec[e];
        int2 r1 = rec[e + 4];
        float w0 = __int_as_float(r0.y);
        float w1 = __int_as_float(r1.y);
        bf16x8 h0 = *(const bf16x8*)&H1[(size_t)r0.x * DF + fo];
        bf16x8 h1 = *(const bf16x8*)&H1[(size_t)r1.x * DF + fo];
#pragma unroll
        for (int i = 0; i < 8; ++i) a[i] += (float)h0[i] * w0;
#pragma unroll
        for (int i = 0; i < 8; ++i) a[i] += (float)h1[i] * w1;
    }
    for (; e < e1; e += 4) {
        int2 r = rec[e];
        float w = __int_as_float(r.y);
        bf16x8 h = *(const bf16x8*)&H1[(size_t)r.x * DF + fo];
#pragma unroll
        for (int i = 0; i < 8; ++i) a[i] += (float)h[i] * w;
    }
#pragma unroll
    for (int i = 0; i < 8; ++i) {
        a[i] += __shfl_xor(a[i], 16);
        a[i] += __shfl_xor(a[i], 32);
        a[i] = fmaxf(a[i], 0.f);               // ReLU (all lanes now hold row)
    }

    // mini-GEMM: lane computes 4 classes (g*4..g*4+3) over its 8 feats
    float p[4];
#pragma unroll
    for (int j = 0; j < 4; ++j) {
        bf16x8 wr = *(const bf16x8*)&W2T[(size_t)(g * 4 + j) * DF + fo];
        float s = 0.f;
#pragma unroll
        for (int i = 0; i < 8; ++i) s += a[i] * (float)wr[i];
        p[j] = s;
    }
#pragma unroll
    for (int o = 1; o <= 8; o <<= 1) {
#pragma unroll
        for (int j = 0; j < 4; ++j) p[j] += __shfl_xor(p[j], o);
    }
    if (l16 == 0) {
        f32x4 o4 = {p[0], p[1], p[2], p[3]};
        *(f32x4*)&H2[(size_t)n * NC + g * 4] = o4;
    }
}

// ---------------- agg layer 2: 8 edges in flight, fused sigmoid -> OUT ------
__global__ __launch_bounds__(256) void k_agg2(const float* __restrict__ H2,
                                              const float* __restrict__ dis,
                                              const float* __restrict__ b2,
                                              const int* __restrict__ off,
                                              const int2* __restrict__ rec,
                                              float* __restrict__ OUT) {
    const int wid = threadIdx.x >> 6, lane = threadIdx.x & 63;
    const int n = blockIdx.x * 4 + wid;
    if (n >= NN) return;

    const int g = lane >> 3, l8 = lane & 7;
    float ax = 0.f, ay = 0.f;
    const int e0 = off[n], e1 = off[n + 1];
    for (int e = e0 + g; e < e1; e += 8) {
        int2 r = rec[e];
        float w = __int_as_float(r.y);
        float2 h = *(const float2*)&H2[(size_t)r.x * NC + l8 * 2];
        ax += h.x * w;
        ay += h.y * w;
    }
    ax += __shfl_xor(ax, 8);  ay += __shfl_xor(ay, 8);
    ax += __shfl_xor(ax, 16); ay += __shfl_xor(ay, 16);
    ax += __shfl_xor(ax, 32); ay += __shfl_xor(ay, 32);
    if (g == 0) {
        float dn = dis[n], d2 = dn * dn;
        float2 hs = *(const float2*)&H2[(size_t)n * NC + l8 * 2];
        float2 bb = *(const float2*)&b2[l8 * 2];
        float vx = bb.x + hs.x * d2 + ax;
        float vy = bb.y + hs.y * d2 + ay;
        float2 o = { 1.0f / (1.0f + expf(-vx)), 1.0f / (1.0f + expf(-vy)) };
        *(float2*)&OUT[(size_t)n * NC + l8 * 2] = o;
    }
}

extern "C" void kernel_launch(void* const* d_in, const int* in_sizes, int n_in,
                              void* d_out, int out_size, void* d_ws, size_t ws_size,
                              hipStream_t stream) {
    const float* X  = (const float*)d_in[0];
    const int*   EI = (const int*)d_in[1];
    const float* W1 = (const float*)d_in[2];
    const float* b1 = (const float*)d_in[3];
    const float* W2 = (const float*)d_in[4];
    const float* b2 = (const float*)d_in[5];
    float* OUT = (float*)d_out;

    const int* src = EI;
    const int* dst = EI + NE;

    // workspace layout (bytes)
    char* ws = (char*)d_ws;
    int*    degi    = (int*)(ws);                   // NN            @ 0
    int*    off     = (int*)(ws + 262144);          // NN+1
    int*    part    = (int*)(ws + 524288);          // NBLK
    int*    partoff = (int*)(ws + 528384);          // NBLK
    float*  dis     = (float*)(ws + 532480);        // NN
    __bf16* W1T     = (__bf16*)(ws + 786432);       // 128*128 bf16 = 32 KB
    __bf16* W2T     = (__bf16*)(ws + 819200);       // 16*128 bf16 = 4 KB
    int*    slot    = (int*)(ws + 1048576);         // NE ints = 3.2 MB
    int2*   rec     = (int2*)(ws + 4718592);        // NE int2 = 6.4 MB
    __bf16* H1      = (__bf16*)(ws + 11534336);     // NN*DF bf16 = 12.8 MB
    float*  H2      = (float*)(ws + 24334336);      // NN*NC f32 = 3.2 MB

    const int B = 256;

    k_prep<<<(NN + DF * DF + NC * DF + B - 1) / B, B, 0, stream>>>(degi, W1, W2, W1T, W2T);
    k_gemm1_deg<<<GB + DB, B, 0, stream>>>(X, W1T, H1, dst, degi, slot);
    k_part<<<NBLK, B, 0, stream>>>(degi, part);
    k_scan_part<<<1, B, 0, stream>>>(part, partoff, off);
    k_off<<<NBLK, B, 0, stream>>>(degi, partoff, off, dis);
    k_csr_fill<<<(NE / 2 + B - 1) / B, B, 0, stream>>>(src, dst, slot, dis, off, rec);

    k_agg1g2<<<(NN + 3) / 4, B, 0, stream>>>(H1, dis, b1, W2T, off, rec, H2);
    k_agg2<<<(NN + 3) / 4, B, 0, stream>>>(H2, dis, b2, off, rec, OUT);
}

// Round 8
// 135.263 us; speedup vs baseline: 4.0373x; 1.0484x over previous
//
#include <hip/hip_runtime.h>
#include <math.h>

#define NN 50000
#define NE 800000
#define DF 128
#define NC 16
#define NBLK 200   // scan blocks
#define CHUNK 250  // elements per scan block (NBLK*CHUNK == NN)
#define WLD 136    // padded LDS row stride (bf16 elems): 272B -> 2-way bank alias only

typedef __bf16 bf16x8 __attribute__((ext_vector_type(8)));
typedef __bf16 bf16x4 __attribute__((ext_vector_type(4)));
typedef float  f32x4  __attribute__((ext_vector_type(4)));

#define GB ((NN + 63) / 64)    // gemm1 blocks in fused kernel (782)
#define DB ((NE + 511) / 512)  // deg/slot blocks (2 edges/thread) (1563)

// ---------------- prep: degi=0  +  W1->W1T bf16, W2->W2T bf16 ----------------
__global__ void k_prep(int* __restrict__ degi,
                       const float* __restrict__ W1, const float* __restrict__ W2,
                       __bf16* __restrict__ W1T, __bf16* __restrict__ W2T) {
    int i = blockIdx.x * blockDim.x + threadIdx.x;
    if (i < NN) degi[i] = 0;
    int j = i - NN;
    if (j >= 0 && j < DF * DF) {
        int n = j >> 7, k = j & 127;
        W1T[j] = (__bf16)W1[k * DF + n];
    }
    int jj = j - DF * DF;
    if (jj >= 0 && jj < NC * DF) {
        int n = jj >> 7, k = jj & 127;
        W2T[jj] = (__bf16)W2[k * NC + n];
    }
}

// ---------------- fused: [0,GB) gemm1 (MFMA, LDS-staged W) | deg+slot -------
__global__ __launch_bounds__(256) void k_gemm1_deg(const float* __restrict__ X,
                                                   const __bf16* __restrict__ W1T,
                                                   __bf16* __restrict__ H1,
                                                   const int* __restrict__ dst,
                                                   int* __restrict__ degi,
                                                   int* __restrict__ slot) {
    __shared__ __bf16 wlds[DF * WLD];   // 34 KB
    if (blockIdx.x >= GB) {
        // 2 edges per thread, loads issued before atomics (MLP=2)
        int e0 = (blockIdx.x - GB) * 512 + threadIdx.x;
        int e1 = e0 + 256;
        int d0 = (e0 < NE) ? dst[e0] : 0;
        int d1 = (e1 < NE) ? dst[e1] : 0;
        if (e0 < NE) slot[e0] = atomicAdd(&degi[d0], 1);
        if (e1 < NE) slot[e1] = atomicAdd(&degi[d1], 1);
        return;
    }
    const int wid = threadIdx.x >> 6, lane = threadIdx.x & 63;
    const int m0 = blockIdx.x * 64 + wid * 16;
    const int m = m0 + (lane & 15);
    const int mc = (m < NN) ? m : NN - 1;       // clamped load row
    const int l15 = lane & 15;
    const int kb = (lane >> 4) * 8;             // k-chunk within 32-slice

    // prefetch all 8 X float4 chunks (independent, in flight together)
    float4 xf[8];
#pragma unroll
    for (int q = 0; q < 4; ++q) {
        xf[2 * q]     = *(const float4*)&X[(size_t)mc * DF + q * 32 + kb];
        xf[2 * q + 1] = *(const float4*)&X[(size_t)mc * DF + q * 32 + kb + 4];
    }

    // stage W1T -> LDS (row stride WLD)
    for (int i = threadIdx.x; i < DF * 16; i += 256) {
        int row = i >> 4, c8 = i & 15;
        *(bf16x8*)&wlds[row * WLD + c8 * 8] = ((const bf16x8*)W1T)[i];
    }
    __syncthreads();

    f32x4 acc[8];
#pragma unroll
    for (int nf = 0; nf < 8; ++nf) acc[nf] = (f32x4){0.f, 0.f, 0.f, 0.f};

#pragma unroll
    for (int ks = 0; ks < 4; ++ks) {
        float4 x0 = xf[2 * ks], x1 = xf[2 * ks + 1];
        bf16x8 xa;
        xa[0] = (__bf16)x0.x; xa[1] = (__bf16)x0.y; xa[2] = (__bf16)x0.z; xa[3] = (__bf16)x0.w;
        xa[4] = (__bf16)x1.x; xa[5] = (__bf16)x1.y; xa[6] = (__bf16)x1.z; xa[7] = (__bf16)x1.w;
#pragma unroll
        for (int nf = 0; nf < 8; ++nf) {
            bf16x8 wa = *(const bf16x8*)&wlds[(nf * 16 + l15) * WLD + ks * 32 + kb];
            acc[nf] = __builtin_amdgcn_mfma_f32_16x16x32_bf16(wa, xa, acc[nf], 0, 0, 0);
        }
    }
    if (m < NN) {
#pragma unroll
        for (int nf = 0; nf < 8; ++nf) {
            bf16x4 o;
            o[0] = (__bf16)acc[nf][0]; o[1] = (__bf16)acc[nf][1];
            o[2] = (__bf16)acc[nf][2]; o[3] = (__bf16)acc[nf][3];
            *(bf16x4*)&H1[(size_t)m * DF + nf * 16 + (lane >> 4) * 4] = o;
        }
    }
}

// ---------------- phase 1: per-block partial sums of degi ----------------
__global__ __launch_bounds__(256) void k_part(const int* __restrict__ degi,
                                              int* __restrict__ part) {
    __shared__ int ws[4];
    const int b = blockIdx.x, t = threadIdx.x;
    int s = 0;
    if (t < CHUNK) s = degi[b * CHUNK + t];
    for (int o = 32; o > 0; o >>= 1) s += __shfl_down(s, o);
    if ((t & 63) == 0) ws[t >> 6] = s;
    __syncthreads();
    if (t == 0) part[b] = ws[0] + ws[1] + ws[2] + ws[3];
}

// ---------------- phase 2: scan the NBLK partials ----------------
__global__ __launch_bounds__(256) void k_scan_part(const int* __restrict__ part,
                                                   int* __restrict__ partoff,
                                                   int* __restrict__ off) {
    __shared__ int s[256];
    const int t = threadIdx.x;
    int v = (t < NBLK) ? part[t] : 0;
    s[t] = v;
    __syncthreads();
    for (int o = 1; o < 256; o <<= 1) {
        int x = (t >= o) ? s[t - o] : 0;
        __syncthreads();
        s[t] += x;
        __syncthreads();
    }
    if (t < NBLK) partoff[t] = s[t] - v;
    if (t == 255) off[NN] = s[255];
}

// ---------------- phase 3: block-local scan -> offsets; fused dis ----------
__global__ __launch_bounds__(256) void k_off(const int* __restrict__ degi,
                                             const int* __restrict__ partoff,
                                             int* __restrict__ off,
                                             float* __restrict__ dis) {
    __shared__ int s[256];
    const int b = blockIdx.x, t = threadIdx.x;
    const int idx = b * CHUNK + t;
    int v = (t < CHUNK) ? degi[idx] : 0;
    s[t] = v;
    __syncthreads();
    for (int o = 1; o < 256; o <<= 1) {
        int x = (t >= o) ? s[t - o] : 0;
        __syncthreads();
        s[t] += x;
        __syncthreads();
    }
    if (t < CHUNK) {
        off[idx] = partoff[b] + s[t] - v;
        dis[idx] = rsqrtf((float)(v + 1));   // +1 self-loop
    }
}

// ---------------- CSR fill (atomic-free): rec[off[d]+slot[e]] = (s, w) ------
__global__ void k_csr_fill(const int* __restrict__ src, const int* __restrict__ dst,
                           const int* __restrict__ slot,
                           const float* __restrict__ dis, const int* __restrict__ off,
                           int2* __restrict__ rec) {
    int e = (blockIdx.x * blockDim.x + threadIdx.x) * 2;
#pragma unroll
    for (int u = 0; u < 2; ++u, ++e) {
        if (e < NE) {
            int s = src[e], d = dst[e];
            float w = dis[s] * dis[d];
            rec[off[d] + slot[e]] = make_int2(s, __float_as_int(w));
        }
    }
}

// ---------------- agg1 + gemm2 fused: one node per wave ---------------------
__global__ __launch_bounds__(256) void k_agg1g2(const __bf16* __restrict__ H1,
                                                const float* __restrict__ dis,
                                                const float* __restrict__ b1,
                                                const __bf16* __restrict__ W2T,
                                                const int* __restrict__ off,
                                                const int2* __restrict__ rec,
                                                float* __restrict__ H2) {
    const int wid = threadIdx.x >> 6, lane = threadIdx.x & 63;
    const int n = blockIdx.x * 4 + wid;
    if (n >= NN) return;
    const int g = lane >> 4, l16 = lane & 15;
    const int fo = l16 * 8;

    float a[8];
    if (g == 0) {
        float dn = dis[n], d2 = dn * dn;
        float4 b0 = *(const float4*)&b1[fo];
        float4 b4 = *(const float4*)&b1[fo + 4];
        bf16x8 hs = *(const bf16x8*)&H1[(size_t)n * DF + fo];
        a[0] = b0.x + (float)hs[0] * d2;
        a[1] = b0.y + (float)hs[1] * d2;
        a[2] = b0.z + (float)hs[2] * d2;
        a[3] = b0.w + (float)hs[3] * d2;
        a[4] = b4.x + (float)hs[4] * d2;
        a[5] = b4.y + (float)hs[5] * d2;
        a[6] = b4.z + (float)hs[6] * d2;
        a[7] = b4.w + (float)hs[7] * d2;
    } else {
#pragma unroll
        for (int i = 0; i < 8; ++i) a[i] = 0.f;
    }

    const int e0 = off[n], e1 = off[n + 1];
    int e = e0 + g;
    for (; e + 4 < e1; e += 8) {
        int2 r0 = rec[e];
        int2 r1 = rec[e + 4];
        float w0 = __int_as_float(r0.y);
        float w1 = __int_as_float(r1.y);
        bf16x8 h0 = *(const bf16x8*)&H1[(size_t)r0.x * DF + fo];
        bf16x8 h1 = *(const bf16x8*)&H1[(size_t)r1.x * DF + fo];
#pragma unroll
        for (int i = 0; i < 8; ++i) a[i] += (float)h0[i] * w0;
#pragma unroll
        for (int i = 0; i < 8; ++i) a[i] += (float)h1[i] * w1;
    }
    for (; e < e1; e += 4) {
        int2 r = rec[e];
        float w = __int_as_float(r.y);
        bf16x8 h = *(const bf16x8*)&H1[(size_t)r.x * DF + fo];
#pragma unroll
        for (int i = 0; i < 8; ++i) a[i] += (float)h[i] * w;
    }
#pragma unroll
    for (int i = 0; i < 8; ++i) {
        a[i] += __shfl_xor(a[i], 16);
        a[i] += __shfl_xor(a[i], 32);
        a[i] = fmaxf(a[i], 0.f);               // ReLU (all lanes now hold row)
    }

    // mini-GEMM: lane computes 4 classes (g*4..g*4+3) over its 8 feats
    float p[4];
#pragma unroll
    for (int j = 0; j < 4; ++j) {
        bf16x8 wr = *(const bf16x8*)&W2T[(size_t)(g * 4 + j) * DF + fo];
        float s = 0.f;
#pragma unroll
        for (int i = 0; i < 8; ++i) s += a[i] * (float)wr[i];
        p[j] = s;
    }
#pragma unroll
    for (int o = 1; o <= 8; o <<= 1) {
#pragma unroll
        for (int j = 0; j < 4; ++j) p[j] += __shfl_xor(p[j], o);
    }
    if (l16 == 0) {
        f32x4 o4 = {p[0], p[1], p[2], p[3]};
        *(f32x4*)&H2[(size_t)n * NC + g * 4] = o4;
    }
}

// ---------------- agg layer 2: 8 edges in flight, fused sigmoid -> OUT ------
__global__ __launch_bounds__(256) void k_agg2(const float* __restrict__ H2,
                                              const float* __restrict__ dis,
                                              const float* __restrict__ b2,
                                              const int* __restrict__ off,
                                              const int2* __restrict__ rec,
                                              float* __restrict__ OUT) {
    const int wid = threadIdx.x >> 6, lane = threadIdx.x & 63;
    const int n = blockIdx.x * 4 + wid;
    if (n >= NN) return;

    const int g = lane >> 3, l8 = lane & 7;
    float ax = 0.f, ay = 0.f;
    const int e0 = off[n], e1 = off[n + 1];
    for (int e = e0 + g; e < e1; e += 8) {
        int2 r = rec[e];
        float w = __int_as_float(r.y);
        float2 h = *(const float2*)&H2[(size_t)r.x * NC + l8 * 2];
        ax += h.x * w;
        ay += h.y * w;
    }
    ax += __shfl_xor(ax, 8);  ay += __shfl_xor(ay, 8);
    ax += __shfl_xor(ax, 16); ay += __shfl_xor(ay, 16);
    ax += __shfl_xor(ax, 32); ay += __shfl_xor(ay, 32);
    if (g == 0) {
        float dn = dis[n], d2 = dn * dn;
        float2 hs = *(const float2*)&H2[(size_t)n * NC + l8 * 2];
        float2 bb = *(const float2*)&b2[l8 * 2];
        float vx = bb.x + hs.x * d2 + ax;
        float vy = bb.y + hs.y * d2 + ay;
        float2 o = { 1.0f / (1.0f + expf(-vx)), 1.0f / (1.0f + expf(-vy)) };
        *(float2*)&OUT[(size_t)n * NC + l8 * 2] = o;
    }
}

extern "C" void kernel_launch(void* const* d_in, const int* in_sizes, int n_in,
                              void* d_out, int out_size, void* d_ws, size_t ws_size,
                              hipStream_t stream) {
    const float* X  = (const float*)d_in[0];
    const int*   EI = (const int*)d_in[1];
    const float* W1 = (const float*)d_in[2];
    const float* b1 = (const float*)d_in[3];
    const float* W2 = (const float*)d_in[4];
    const float* b2 = (const float*)d_in[5];
    float* OUT = (float*)d_out;

    const int* src = EI;
    const int* dst = EI + NE;

    // workspace layout (bytes)
    char* ws = (char*)d_ws;
    int*    degi    = (int*)(ws);                   // NN            @ 0
    int*    off     = (int*)(ws + 262144);          // NN+1
    int*    part    = (int*)(ws + 524288);          // NBLK
    int*    partoff = (int*)(ws + 528384);          // NBLK
    float*  dis     = (float*)(ws + 532480);        // NN
    __bf16* W1T     = (__bf16*)(ws + 786432);       // 128*128 bf16 = 32 KB
    __bf16* W2T     = (__bf16*)(ws + 819200);       // 16*128 bf16 = 4 KB
    int*    slot    = (int*)(ws + 1048576);         // NE ints = 3.2 MB
    int2*   rec     = (int2*)(ws + 4718592);        // NE int2 = 6.4 MB
    __bf16* H1      = (__bf16*)(ws + 11534336);     // NN*DF bf16 = 12.8 MB
    float*  H2      = (float*)(ws + 24334336);      // NN*NC f32 = 3.2 MB

    const int B = 256;

    k_prep<<<(NN + DF * DF + NC * DF + B - 1) / B, B, 0, stream>>>(degi, W1, W2, W1T, W2T);
    k_gemm1_deg<<<GB + DB, B, 0, stream>>>(X, W1T, H1, dst, degi, slot);
    k_part<<<NBLK, B, 0, stream>>>(degi, part);
    k_scan_part<<<1, B, 0, stream>>>(part, partoff, off);
    k_off<<<NBLK, B, 0, stream>>>(degi, partoff, off, dis);
    k_csr_fill<<<(NE / 2 + B - 1) / B, B, 0, stream>>>(src, dst, slot, dis, off, rec);

    k_agg1g2<<<(NN + 3) / 4, B, 0, stream>>>(H1, dis, b1, W2T, off, rec, H2);
    k_agg2<<<(NN + 3) / 4, B, 0, stream>>>(H2, dis, b2, off, rec, OUT);
}